// Round 6
// baseline (236.049 us; speedup 1.0000x reference)
//
#include <hip/hip_runtime.h>
#include <math.h>

#define NSEGB 160
#define NTEMB 32
#define NBLK  (NSEGB + NTEMB)   // 192 blocks <= 256 CUs -> co-residency guaranteed
#define NF 147

__device__ __forceinline__ void gbar(int* cnt) {
    __syncthreads();
    if (threadIdx.x == 0) {
        __threadfence();
        atomicAdd(cnt, 1);
        while (atomicAdd(cnt, 0) < NBLK) { }
        __threadfence();
    }
    __syncthreads();
}

__device__ __forceinline__ float agload(const float* p) {
    return __hip_atomic_load(p, __ATOMIC_RELAXED, __HIP_MEMORY_SCOPE_AGENT);
}

// ---------------------------------------------------------------------------
// Fused kernel, 192 blocks x 256 threads, persistent with 3 grid barriers.
//   blocks 0..159 ("seg"):  4 segments each. geometry -> pool(LDS) -> fc1(regs)
//                           | b1 | +tg, stats1 | b2 | bn1+relu+fc2, stats2
//                           | b3 | bn2+relu+fc3 -> out
//   blocks 160..191 ("temb"): e -> L1 -> temb2 -> tg  (all LDS-local), then
//                           spin through the 3 barriers.
// Cross-block tensors: tg(32x256), stats1(512), stats2(256), counters — all
// via device-scope atomics / agent-scope loads (XCD-coherent).
// ---------------------------------------------------------------------------
__global__ __launch_bounds__(256) void kfused(
    const float* __restrict__ noise, const int* __restrict__ tsteps,
    const float* __restrict__ pcs, const int* __restrict__ bl,
    const float* __restrict__ pe_w, const float* __restrict__ pe_b,
    const float* __restrict__ t_w1, const float* __restrict__ t_b1,
    const float* __restrict__ t_w2, const float* __restrict__ t_b2,
    const float* __restrict__ pfc_w, const float* __restrict__ pfc_b,
    const float* __restrict__ o_w1, const float* __restrict__ o_b1,
    const float* __restrict__ bn1_g, const float* __restrict__ bn1_b,
    const float* __restrict__ o_w2, const float* __restrict__ o_b2,
    const float* __restrict__ bn2_g, const float* __restrict__ bn2_b,
    const float* __restrict__ o_w3, const float* __restrict__ o_b3,
    float* __restrict__ tg, float* __restrict__ stats1,
    float* __restrict__ stats2, int* __restrict__ cnts,
    float* __restrict__ out)
{
    // shm layout (seg role): pool[4][512] = [0..2048) ; nbs[4][148] = [2048..2640)
    //   after b1: rowsA[4][256] = [0..1024) ; fc2 partials red[2][4][128] = [1024..2048)
    //   after fc2: rowsB[4][128] = [0..512)
    // shm layout (temb role): e = [0..512) ; h1 = [512..1024) ; temb2 = [0..512)
    __shared__ float shm[2688];
    __shared__ float np7s[4][8];
    __shared__ float wsum[4][3];
    __shared__ float rms[4][3];

    int blk = blockIdx.x, tid = threadIdx.x;
    int s0 = blk * 4;
    float acc0 = 0.f, acc1 = 0.f, acc2 = 0.f, acc3 = 0.f;

    if (blk < NSEGB) {
        // ---- geometry: wave w handles segment s0+w ----
        int w = tid >> 6, lane = tid & 63;
        {
            const float* pbase = pcs + (size_t)(s0 + w) * 750;
            float sx = 0.f, sy = 0.f, sz = 0.f;
            #pragma unroll
            for (int it = 0; it < 4; it++) {
                int q = lane + it * 64;
                if (q < 250) {
                    const float* p = pbase + q * 3;
                    sx += p[0]; sy += p[1]; sz += p[2];
                }
            }
            for (int off = 32; off >= 1; off >>= 1) {
                sx += __shfl_down(sx, off, 64);
                sy += __shfl_down(sy, off, 64);
                sz += __shfl_down(sz, off, 64);
            }
            if (lane == 0) { wsum[w][0] = sx; wsum[w][1] = sy; wsum[w][2] = sz; }
        }
        if (tid < 28) np7s[tid / 7][tid % 7] = noise[s0 * 7 + tid];
        __syncthreads();
        if (tid < 4) {
            float inv = 1.f / (float)bl[s0 + tid];
            float mx = wsum[tid][0] * inv, my = wsum[tid][1] * inv, mz = wsum[tid][2] * inv;
            float qw = np7s[tid][3], qx = np7s[tid][4], qy = np7s[tid][5], qz = np7s[tid][6];
            float qn = rsqrtf(qw * qw + qx * qx + qy * qy + qz * qz);
            qw *= qn; qx *= qn; qy *= qn; qz *= qn;
            float tx = 2.f * (qy * mz - qz * my);
            float ty = 2.f * (qz * mx - qx * mz);
            float tz = 2.f * (qx * my - qy * mx);
            rms[tid][0] = mx + qw * tx + (qy * tz - qz * ty) + np7s[tid][0];
            rms[tid][1] = my + qw * ty + (qz * tx - qx * tz) + np7s[tid][1];
            rms[tid][2] = mz + qw * tz + (qx * ty - qy * tx) + np7s[tid][2];
        }
        // ---- nerf embed into LDS nbs ----
        for (int u = tid; u < 4 * NF; u += 256) {
            int r = u / NF, f = u % NF;
            float v;
            if (f < 7) v = np7s[r][f];
            else {
                int j = f - 7;
                int fi = j / 14, x = j % 14;
                float band = (float)(1 << fi);
                v = (x < 7) ? sinf(np7s[r][x] * band) : cosf(np7s[r][x - 7] * band);
            }
            shm[2048 + r * 148 + f] = v;
        }
        __syncthreads();
        // ---- pool rows (4x512) in LDS ----
        #pragma unroll
        for (int h = 0; h < 2; h++) {
            int j = h * 256 + tid;
            float base = pfc_b[j] + pe_b[j];
            float w0 = pe_w[j], w1 = pe_w[512 + j], w2 = pe_w[1024 + j];
            float a0 = base + rms[0][0] * w0 + rms[0][1] * w1 + rms[0][2] * w2;
            float a1 = base + rms[1][0] * w0 + rms[1][1] * w1 + rms[1][2] * w2;
            float a2 = base + rms[2][0] * w0 + rms[2][1] * w1 + rms[2][2] * w2;
            float a3 = base + rms[3][0] * w0 + rms[3][1] * w1 + rms[3][2] * w2;
            #pragma unroll 7
            for (int k = 0; k < NF; k++) {
                float wv = pfc_w[k * 512 + j];
                a0 += shm[2048 + k] * wv;
                a1 += shm[2048 + 148 + k] * wv;
                a2 += shm[2048 + 296 + k] * wv;
                a3 += shm[2048 + 444 + k] * wv;
            }
            shm[j] = a0; shm[512 + j] = a1; shm[1024 + j] = a2; shm[1536 + j] = a3;
        }
        __syncthreads();
        // ---- fc1: 4 rows x col tid, k=512 (acc in regs; no bias — it's in tg) ----
        #pragma unroll 8
        for (int k = 0; k < 512; k++) {
            float wv = o_w1[k * 256 + tid];
            acc0 += shm[k] * wv;
            acc1 += shm[512 + k] * wv;
            acc2 += shm[1024 + k] * wv;
            acc3 += shm[1536 + k] * wv;
        }
    } else {
        // ---- temb role: block-local chain e -> L1 -> temb2 -> tg ----
        int b = blk - NSEGB;
        float tf = (float)tsteps[b];
        float f = expf(-9.210340371976184f * (float)tid * (1.f / 256.f));
        float sn, cs;
        sincosf(tf * f, &sn, &cs);
        shm[tid] = cs; shm[256 + tid] = sn;
        __syncthreads();
        float a0 = 0.f, a1 = 0.f;
        #pragma unroll 4
        for (int k = 0; k < 512; k++) {
            float s = shm[k];
            a0 += s * t_w1[k * 512 + tid];
            a1 += s * t_w1[k * 512 + 256 + tid];
        }
        a0 += t_b1[tid]; a1 += t_b1[256 + tid];
        shm[512 + tid] = a0 / (1.f + expf(-a0));
        shm[512 + 256 + tid] = a1 / (1.f + expf(-a1));
        __syncthreads();
        a0 = 0.f; a1 = 0.f;
        #pragma unroll 4
        for (int k = 0; k < 512; k++) {
            float s = shm[512 + k];
            a0 += s * t_w2[k * 512 + tid];
            a1 += s * t_w2[k * 512 + 256 + tid];
        }
        a0 += t_b2[tid]; a1 += t_b2[256 + tid];
        __syncthreads();              // everyone done reading h1 region before e-region reuse is safe
        shm[tid] = a0; shm[256 + tid] = a1;   // temb2 into [0..512)
        __syncthreads();
        float acc = o_b1[tid];
        #pragma unroll 8
        for (int k = 0; k < 512; k++) acc += shm[k] * o_w1[k * 256 + tid];
        __hip_atomic_store(&tg[b * 256 + tid], acc, __ATOMIC_RELAXED, __HIP_MEMORY_SCOPE_AGENT);
    }

    gbar(&cnts[0]);

    if (blk < NSEGB) {
        // ---- assemble rows = fc1 + tg, stats1 atomics, stash rows in LDS ----
        int c = tid;
        float r0v = acc0 + agload(&tg[((s0 + 0) / 20) * 256 + c]);
        float r1v = acc1 + agload(&tg[((s0 + 1) / 20) * 256 + c]);
        float r2v = acc2 + agload(&tg[((s0 + 2) / 20) * 256 + c]);
        float r3v = acc3 + agload(&tg[((s0 + 3) / 20) * 256 + c]);
        atomicAdd(&stats1[c], r0v + r1v + r2v + r3v);
        atomicAdd(&stats1[256 + c], r0v * r0v + r1v * r1v + r2v * r2v + r3v * r3v);
        shm[c] = r0v; shm[256 + c] = r1v; shm[512 + c] = r2v; shm[768 + c] = r3v;
    }

    gbar(&cnts[1]);

    if (blk < NSEGB) {
        // ---- bn1 + relu (per-thread column), then fc2 with 2-way k-split ----
        {
            int c = tid;
            float m = agload(&stats1[c]) * (1.f / 640.f);
            float v = agload(&stats1[256 + c]) * (1.f / 640.f) - m * m;
            float sc = rsqrtf(v + 1e-5f) * bn1_g[c];
            float sh = bn1_b[c] - m * sc;
            #pragma unroll
            for (int r = 0; r < 4; r++) {
                float x = shm[r * 256 + c] * sc + sh;
                shm[r * 256 + c] = x > 0.f ? x : 0.f;
            }
        }
        __syncthreads();
        {
            int c2 = tid & 127, ks = tid >> 7;
            float b0 = 0.f, b1 = 0.f, b2 = 0.f, b3 = 0.f;
            int kbase = ks * 128;
            #pragma unroll 8
            for (int kk = 0; kk < 128; kk++) {
                int k = kbase + kk;
                float wv = o_w2[k * 128 + c2];
                b0 += shm[k] * wv;
                b1 += shm[256 + k] * wv;
                b2 += shm[512 + k] * wv;
                b3 += shm[768 + k] * wv;
            }
            shm[1024 + (ks * 4 + 0) * 128 + c2] = b0;
            shm[1024 + (ks * 4 + 1) * 128 + c2] = b1;
            shm[1024 + (ks * 4 + 2) * 128 + c2] = b2;
            shm[1024 + (ks * 4 + 3) * 128 + c2] = b3;
        }
        __syncthreads();
        if (tid < 128) {
            float bb = o_b2[tid];
            float h0 = shm[1024 + tid]       + shm[1536 + tid]       + bb;
            float h1v = shm[1024 + 128 + tid] + shm[1536 + 128 + tid] + bb;
            float h2v = shm[1024 + 256 + tid] + shm[1536 + 256 + tid] + bb;
            float h3v = shm[1024 + 384 + tid] + shm[1536 + 384 + tid] + bb;
            atomicAdd(&stats2[tid], h0 + h1v + h2v + h3v);
            atomicAdd(&stats2[128 + tid], h0 * h0 + h1v * h1v + h2v * h2v + h3v * h3v);
            shm[tid] = h0; shm[128 + tid] = h1v; shm[256 + tid] = h2v; shm[384 + tid] = h3v;
        }
    }

    gbar(&cnts[2]);

    if (blk < NSEGB) {
        if (tid < 128) {
            float m = agload(&stats2[tid]) * (1.f / 640.f);
            float v = agload(&stats2[128 + tid]) * (1.f / 640.f) - m * m;
            float sc = rsqrtf(v + 1e-5f) * bn2_g[tid];
            float sh = bn2_b[tid] - m * sc;
            #pragma unroll
            for (int r = 0; r < 4; r++) {
                float x = shm[r * 128 + tid] * sc + sh;
                shm[r * 128 + tid] = x > 0.f ? x : 0.f;
            }
        }
        __syncthreads();
        if (tid < 28) {
            int r = tid / 7, j = tid % 7;
            float a3 = o_b3[j];
            #pragma unroll 8
            for (int k = 0; k < 128; k++) a3 += shm[r * 128 + k] * o_w3[k * 7 + j];
            out[(s0 + r) * 7 + j] = a3;
        }
    }
}

extern "C" void kernel_launch(void* const* d_in, const int* in_sizes, int n_in,
                              void* d_out, int out_size, void* d_ws, size_t ws_size,
                              hipStream_t stream) {
    const float* noise = (const float*)d_in[0];
    const int* tsteps = (const int*)d_in[1];
    const float* pcs = (const float*)d_in[2];
    const int* bl = (const int*)d_in[4];
    const float* pe_w = (const float*)d_in[5];
    const float* pe_b = (const float*)d_in[6];
    const float* t_w1 = (const float*)d_in[7];
    const float* t_b1 = (const float*)d_in[8];
    const float* t_w2 = (const float*)d_in[9];
    const float* t_b2 = (const float*)d_in[10];
    const float* pfc_w = (const float*)d_in[11];
    const float* pfc_b = (const float*)d_in[12];
    const float* o_w1 = (const float*)d_in[13];
    const float* o_b1 = (const float*)d_in[14];
    const float* bn1_g = (const float*)d_in[15];
    const float* bn1_b = (const float*)d_in[16];
    const float* o_w2 = (const float*)d_in[17];
    const float* o_b2 = (const float*)d_in[18];
    const float* bn2_g = (const float*)d_in[19];
    const float* bn2_b = (const float*)d_in[20];
    const float* o_w3 = (const float*)d_in[21];
    const float* o_b3 = (const float*)d_in[22];

    float* ws = (float*)d_ws;
    float* tg     = ws;            // 32*256 = 8192
    float* stats1 = ws + 8192;     // 512
    float* stats2 = ws + 8704;     // 256
    int*   cnts   = (int*)(ws + 8960); // 8 ints

    // zero stats + barrier counters (graph-capturable async memset)
    hipMemsetAsync(stats1, 0, (512 + 256 + 8) * sizeof(float), stream);

    kfused<<<NBLK, 256, 0, stream>>>(noise, tsteps, pcs, bl, pe_w, pe_b,
                                     t_w1, t_b1, t_w2, t_b2, pfc_w, pfc_b,
                                     o_w1, o_b1, bn1_g, bn1_b, o_w2, o_b2,
                                     bn2_g, bn2_b, o_w3, o_b3,
                                     tg, stats1, stats2, cnts, (float*)d_out);
}

// Round 7
// 193.178 us; speedup vs baseline: 1.2219x; 1.2219x over previous
//
#include <hip/hip_runtime.h>
#include <math.h>

#define NF 147

// ---------------------------------------------------------------------------
// kT (259 blocks x 256): everything that depends only on tsteps / weights.
//   0..127   h1 = silu(e @ t_w1 + t_b1)   (32 b x 4 j-quarters, k-split 2)
//   128..255 M = t_w2 @ o_w1              (512x256; 4 rows/block, float4 cols)
//   256..257 cv = t_b2 @ o_w1 + o_b1      (2 c-halves, k-split 2)
//   258      zero stats[768] + 2 barrier counters
// ---------------------------------------------------------------------------
__global__ __launch_bounds__(256) void kT(
    const int* __restrict__ tsteps,
    const float* __restrict__ t_w1, const float* __restrict__ t_b1,
    const float* __restrict__ t_w2, const float* __restrict__ t_b2,
    const float* __restrict__ o_w1, const float* __restrict__ o_b1,
    float* __restrict__ h1, float* __restrict__ Mm, float* __restrict__ cv,
    int* __restrict__ statsz)
{
    __shared__ float sh[768];
    int blk = blockIdx.x, tid = threadIdx.x;

    if (blk < 128) {
        int b = blk >> 2, jq = blk & 3;
        float* e = sh;             // [512]
        float* red = sh + 512;     // [2][128]
        float tf = (float)tsteps[b];
        float f = expf(-9.210340371976184f * (float)tid * (1.f / 256.f));
        float sn, cs;
        sincosf(tf * f, &sn, &cs);
        e[tid] = cs;
        e[tid + 256] = sn;
        __syncthreads();
        int jj = tid & 127, j = jq * 128 + jj;
        int ks = tid >> 7, k0 = ks << 8;
        float acc = 0.f;
        #pragma unroll 8
        for (int k = k0; k < k0 + 256; k++) acc += e[k] * t_w1[k * 512 + j];
        red[ks * 128 + jj] = acc;
        __syncthreads();
        if (tid < 128) {
            float v = red[tid] + red[128 + tid] + t_b1[jq * 128 + tid];
            h1[b * 512 + jq * 128 + tid] = v / (1.f + expf(-v));
        }
    } else if (blk < 256) {
        int m = blk - 128;
        int kr = m * 4 + (tid >> 6);
        int c4 = (tid & 63) << 2;
        const float* t2row = t_w2 + (size_t)kr * 512;
        float4 acc = {0.f, 0.f, 0.f, 0.f};
        #pragma unroll 4
        for (int j = 0; j < 512; j++) {
            float4 w = *(const float4*)&o_w1[j * 256 + c4];
            float t2 = t2row[j];
            acc.x += t2 * w.x; acc.y += t2 * w.y; acc.z += t2 * w.z; acc.w += t2 * w.w;
        }
        *(float4*)&Mm[kr * 256 + c4] = acc;
    } else if (blk < 258) {
        int ch = blk - 256;
        int cc = tid & 127, c = ch * 128 + cc;
        int ks = tid >> 7, k0 = ks << 8;
        float acc = 0.f;
        #pragma unroll 8
        for (int j = k0; j < k0 + 256; j++) acc += t_b2[j] * o_w1[j * 256 + c];
        sh[tid] = acc;
        __syncthreads();
        if (tid < 128) cv[c] = sh[tid] + sh[128 + tid] + o_b1[c];
    } else {
        for (int z = tid; z < 772; z += 256) statsz[z] = 0;
    }
}

// ---------------------------------------------------------------------------
// kS (224 blocks x 256):
//   0..159   seg-blocks, 4 segments each: geometry (1 wave/segment) -> nerf ->
//            pool rows (4x512, LDS) -> fc1 with 4-row register blocking ->
//            g1[s][256] (no bias/temb — added in kCD via tg)
//   160..223 tg[b][c-half] = h1[b,:] @ M[:,c] + cv[c]   (32 b x 2 halves, k-split 2)
// ---------------------------------------------------------------------------
__global__ __launch_bounds__(256) void kS(
    const float* __restrict__ noise, const float* __restrict__ pcs,
    const int* __restrict__ bl,
    const float* __restrict__ pe_w, const float* __restrict__ pe_b,
    const float* __restrict__ pfc_w, const float* __restrict__ pfc_b,
    const float* __restrict__ o_w1,
    const float* __restrict__ h1, const float* __restrict__ Mm,
    const float* __restrict__ cv,
    float* __restrict__ g1, float* __restrict__ tg)
{
    __shared__ float shm[2640];   // pool[4][512] | nbs 4x148 at 2048..2640
    __shared__ float np7s[4][8];
    __shared__ float wsum[4][3];
    __shared__ float rms[4][3];
    int blk = blockIdx.x, tid = threadIdx.x;

    if (blk < 160) {
        int s0 = blk * 4;
        int w = tid >> 6, lane = tid & 63;
        {
            const float* pbase = pcs + (size_t)(s0 + w) * 750;
            float sx = 0.f, sy = 0.f, sz = 0.f;
            #pragma unroll
            for (int it = 0; it < 4; it++) {
                int q = lane + it * 64;
                if (q < 250) {
                    const float* p = pbase + q * 3;
                    sx += p[0]; sy += p[1]; sz += p[2];
                }
            }
            for (int off = 32; off >= 1; off >>= 1) {
                sx += __shfl_down(sx, off, 64);
                sy += __shfl_down(sy, off, 64);
                sz += __shfl_down(sz, off, 64);
            }
            if (lane == 0) { wsum[w][0] = sx; wsum[w][1] = sy; wsum[w][2] = sz; }
        }
        if (tid < 28) np7s[tid / 7][tid % 7] = noise[s0 * 7 + tid];
        __syncthreads();
        if (tid < 4) {
            float inv = 1.f / (float)bl[s0 + tid];
            float mx = wsum[tid][0] * inv, my = wsum[tid][1] * inv, mz = wsum[tid][2] * inv;
            float qw = np7s[tid][3], qx = np7s[tid][4], qy = np7s[tid][5], qz = np7s[tid][6];
            float qn = rsqrtf(qw * qw + qx * qx + qy * qy + qz * qz);
            qw *= qn; qx *= qn; qy *= qn; qz *= qn;
            float tx = 2.f * (qy * mz - qz * my);
            float ty = 2.f * (qz * mx - qx * mz);
            float tz = 2.f * (qx * my - qy * mx);
            rms[tid][0] = mx + qw * tx + (qy * tz - qz * ty) + np7s[tid][0];
            rms[tid][1] = my + qw * ty + (qz * tx - qx * tz) + np7s[tid][1];
            rms[tid][2] = mz + qw * tz + (qx * ty - qy * tx) + np7s[tid][2];
        }
        for (int u = tid; u < 4 * NF; u += 256) {
            int r = u / NF, f = u % NF;
            float v;
            if (f < 7) v = np7s[r][f];
            else {
                int j = f - 7;
                int fi = j / 14, x = j % 14;
                float band = (float)(1 << fi);
                v = (x < 7) ? sinf(np7s[r][x] * band) : cosf(np7s[r][x - 7] * band);
            }
            shm[2048 + r * 148 + f] = v;
        }
        __syncthreads();
        #pragma unroll
        for (int h = 0; h < 2; h++) {
            int j = h * 256 + tid;
            float base = pfc_b[j] + pe_b[j];
            float w0 = pe_w[j], w1 = pe_w[512 + j], w2 = pe_w[1024 + j];
            float a0 = base + rms[0][0] * w0 + rms[0][1] * w1 + rms[0][2] * w2;
            float a1 = base + rms[1][0] * w0 + rms[1][1] * w1 + rms[1][2] * w2;
            float a2 = base + rms[2][0] * w0 + rms[2][1] * w1 + rms[2][2] * w2;
            float a3 = base + rms[3][0] * w0 + rms[3][1] * w1 + rms[3][2] * w2;
            #pragma unroll 7
            for (int k = 0; k < NF; k++) {
                float wv = pfc_w[k * 512 + j];
                a0 += shm[2048 + k] * wv;
                a1 += shm[2048 + 148 + k] * wv;
                a2 += shm[2048 + 296 + k] * wv;
                a3 += shm[2048 + 444 + k] * wv;
            }
            shm[j] = a0; shm[512 + j] = a1; shm[1024 + j] = a2; shm[1536 + j] = a3;
        }
        __syncthreads();
        float acc0 = 0.f, acc1 = 0.f, acc2 = 0.f, acc3 = 0.f;
        #pragma unroll 8
        for (int k = 0; k < 512; k++) {
            float wv = o_w1[k * 256 + tid];
            acc0 += shm[k] * wv;
            acc1 += shm[512 + k] * wv;
            acc2 += shm[1024 + k] * wv;
            acc3 += shm[1536 + k] * wv;
        }
        g1[(s0 + 0) * 256 + tid] = acc0;
        g1[(s0 + 1) * 256 + tid] = acc1;
        g1[(s0 + 2) * 256 + tid] = acc2;
        g1[(s0 + 3) * 256 + tid] = acc3;
    } else {
        int q = blk - 160;
        int b = q >> 1, ch = q & 1;
        float* hrow = shm;          // [512]
        float* red = shm + 512;     // [2][128]
        hrow[tid] = h1[b * 512 + tid];
        hrow[tid + 256] = h1[b * 512 + 256 + tid];
        __syncthreads();
        int cc = tid & 127, c = ch * 128 + cc;
        int ks = tid >> 7, k0 = ks << 8;
        float acc = 0.f;
        #pragma unroll 8
        for (int k = k0; k < k0 + 256; k++) acc += hrow[k] * Mm[k * 256 + c];
        red[ks * 128 + cc] = acc;
        __syncthreads();
        if (tid < 128) tg[b * 256 + ch * 128 + tid] = red[tid] + red[128 + tid] + cv[ch * 128 + tid];
    }
}

// ---------------------------------------------------------------------------
// kCD: 80 blocks x 128 threads, co-resident.
//   phase0: rows = g1 + tg ; local col sums -> stats1 atomics
//   barrier1 ; bn1+relu ; fc2 -> acc[8] ; stats2 atomics ; barrier2
//   bn2+relu ; fc3 -> out(640,7)
// ---------------------------------------------------------------------------
__global__ __launch_bounds__(128) void kCD(
    const float* __restrict__ g1, const float* __restrict__ tg,
    float* __restrict__ stats1,
    const float* __restrict__ bn1_g, const float* __restrict__ bn1_b,
    const float* __restrict__ o_w2, const float* __restrict__ o_b2,
    const float* __restrict__ bn2_g, const float* __restrict__ bn2_b,
    const float* __restrict__ o_w3, const float* __restrict__ o_b3,
    float* __restrict__ stats2, int* __restrict__ cntA, int* __restrict__ cntB,
    float* __restrict__ out)
{
    int blk = blockIdx.x, tid = threadIdx.x;
    int r0 = blk * 8;
    __shared__ float rows[8][256];
    __shared__ float scale[256], shift[256];
    __shared__ float rowsB[8][128];
    __shared__ float w3[128 * 7];

    #pragma unroll
    for (int w = 0; w < 4; w++) {
        int idx4 = (tid + w * 128) << 2;
        int r = idx4 >> 8, c = idx4 & 255;
        int s = r0 + r;
        float4 gv = *(const float4*)&g1[s * 256 + c];
        float4 tv = *(const float4*)&tg[(s / 20) * 256 + c];
        gv.x += tv.x; gv.y += tv.y; gv.z += tv.z; gv.w += tv.w;
        *(float4*)&rows[r][c] = gv;
    }
    for (int i = tid; i < 128 * 7; i += 128) w3[i] = o_w3[i];
    __syncthreads();
    for (int c = tid; c < 256; c += 128) {
        float sm = 0.f, ss = 0.f;
        #pragma unroll
        for (int r = 0; r < 8; r++) { float x = rows[r][c]; sm += x; ss += x * x; }
        atomicAdd(&stats1[c], sm);
        atomicAdd(&stats1[256 + c], ss);
    }

    __syncthreads();
    if (tid == 0) {
        __threadfence();
        atomicAdd(cntA, 1);
        while (atomicAdd(cntA, 0) < 80) { }
        __threadfence();
    }
    __syncthreads();

    for (int c = tid; c < 256; c += 128) {
        float m = stats1[c] * (1.f / 640.f);
        float v = stats1[256 + c] * (1.f / 640.f) - m * m;
        float sc = rsqrtf(v + 1e-5f) * bn1_g[c];
        scale[c] = sc;
        shift[c] = bn1_b[c] - m * sc;
    }
    __syncthreads();
    for (int i = tid; i < 2048; i += 128) {
        int r = i >> 8, c = i & 255;
        float x = rows[r][c] * scale[c] + shift[c];
        rows[r][c] = x > 0.f ? x : 0.f;
    }
    __syncthreads();

    float acc[8];
    float bb = o_b2[tid];
    #pragma unroll
    for (int r = 0; r < 8; r++) acc[r] = bb;
    #pragma unroll 8
    for (int k = 0; k < 256; k++) {
        float w = o_w2[k * 128 + tid];
        #pragma unroll
        for (int r = 0; r < 8; r++) acc[r] += rows[r][k] * w;
    }
    float sm = 0.f, ss = 0.f;
    #pragma unroll
    for (int r = 0; r < 8; r++) { sm += acc[r]; ss += acc[r] * acc[r]; }
    atomicAdd(&stats2[tid], sm);
    atomicAdd(&stats2[128 + tid], ss);

    __syncthreads();
    if (tid == 0) {
        __threadfence();
        atomicAdd(cntB, 1);
        while (atomicAdd(cntB, 0) < 80) { }
        __threadfence();
    }
    __syncthreads();

    {
        float m = stats2[tid] * (1.f / 640.f);
        float v = stats2[128 + tid] * (1.f / 640.f) - m * m;
        float sc = rsqrtf(v + 1e-5f) * bn2_g[tid];
        float sh2 = bn2_b[tid] - m * sc;
        #pragma unroll
        for (int r = 0; r < 8; r++) {
            float x = acc[r] * sc + sh2;
            rowsB[r][tid] = x > 0.f ? x : 0.f;
        }
    }
    __syncthreads();
    if (tid < 56) {
        int r = tid / 7, j = tid % 7;
        float a3 = o_b3[j];
        #pragma unroll 8
        for (int k = 0; k < 128; k++) a3 += rowsB[r][k] * w3[k * 7 + j];
        out[(r0 + r) * 7 + j] = a3;
    }
}

extern "C" void kernel_launch(void* const* d_in, const int* in_sizes, int n_in,
                              void* d_out, int out_size, void* d_ws, size_t ws_size,
                              hipStream_t stream) {
    const float* noise = (const float*)d_in[0];
    const int* tsteps = (const int*)d_in[1];
    const float* pcs = (const float*)d_in[2];
    const int* bl = (const int*)d_in[4];
    const float* pe_w = (const float*)d_in[5];
    const float* pe_b = (const float*)d_in[6];
    const float* t_w1 = (const float*)d_in[7];
    const float* t_b1 = (const float*)d_in[8];
    const float* t_w2 = (const float*)d_in[9];
    const float* t_b2 = (const float*)d_in[10];
    const float* pfc_w = (const float*)d_in[11];
    const float* pfc_b = (const float*)d_in[12];
    const float* o_w1 = (const float*)d_in[13];
    const float* o_b1 = (const float*)d_in[14];
    const float* bn1_g = (const float*)d_in[15];
    const float* bn1_b = (const float*)d_in[16];
    const float* o_w2 = (const float*)d_in[17];
    const float* o_b2 = (const float*)d_in[18];
    const float* bn2_g = (const float*)d_in[19];
    const float* bn2_b = (const float*)d_in[20];
    const float* o_w3 = (const float*)d_in[21];
    const float* o_b3 = (const float*)d_in[22];

    float* ws = (float*)d_ws;
    float* h1    = ws + 0;        // 32*512  -> 16384
    float* Mm    = ws + 16384;    // 512*256 -> 147456
    float* cv    = ws + 147456;   // 256     -> 147712
    float* g1    = ws + 147712;   // 640*256 -> 311552
    float* tg    = ws + 311552;   // 32*256  -> 319744
    float* stats = ws + 319744;   // 768 (stats1:512, stats2:256)
    int*   cnt   = (int*)(ws + 320512); // 2 counters (zeroed by kT blk 258)

    kT<<<259, 256, 0, stream>>>(tsteps, t_w1, t_b1, t_w2, t_b2, o_w1, o_b1,
                                h1, Mm, cv, (int*)stats);
    kS<<<224, 256, 0, stream>>>(noise, pcs, bl, pe_w, pe_b, pfc_w, pfc_b,
                                o_w1, h1, Mm, cv, g1, tg);
    kCD<<<80, 128, 0, stream>>>(g1, tg, stats, bn1_g, bn1_b, o_w2, o_b2,
                                bn2_g, bn2_b, o_w3, o_b3,
                                stats + 512, cnt, cnt + 1, (float*)d_out);
}